// Round 4
// baseline (289.063 us; speedup 1.0000x reference)
//
#include <hip/hip_runtime.h>
#include <hip/hip_bf16.h>

typedef short s8v __attribute__((ext_vector_type(8)));   // 8 bf16 (4 VGPRs) MFMA A/B frag
typedef float f4v __attribute__((ext_vector_type(4)));   // MFMA C/D frag

__device__ __forceinline__ unsigned short f2bf(float x) {  // RTNE fp32->bf16 (prep only)
  unsigned u = __builtin_bit_cast(unsigned, x);
  u += 0x7fffu + ((u >> 16) & 1u);
  return (unsigned short)(u >> 16);
}
// fast pack: round-to-nearest-away bf16 pair via v_perm (3 VALU ops)
__device__ __forceinline__ unsigned pk2(float a, float b) {
  unsigned ua = __builtin_bit_cast(unsigned, a) + 0x8000u;
  unsigned ub = __builtin_bit_cast(unsigned, b) + 0x8000u;
  return __builtin_amdgcn_perm(ub, ua, 0x07060302u);  // {ub.hi16, ua.hi16}
}

// ---------------- prep: pack W1^T / W2^T as bf16 A-fragments into ws ----------------
// W1f (8192): frag (h,ks): A[m=16h+l15][k=32ks+8q4+j]; k<13 -> W1 row k; k==13 -> b1;
//   14..15 -> 0; k>=16 -> W1 row k-3.
// W2f (16384): frag (h2,ks), K-permuted to match GEMM1-output register order:
//   k-slot 8q4+j (j<4) -> hidden 32ks+4q4+j ; (j>=4) -> hidden 32ks+16+4q4+(j-4).
__global__ void prep_kernel(const float* __restrict__ W1, const float* __restrict__ b1,
                            const float* __restrict__ W2, unsigned short* __restrict__ wsW) {
  int e = blockIdx.x * 256 + threadIdx.x;   // 96*256 = 24576 exactly
  if (e < 8192) {
    int frag = e >> 9, rem = e & 511, lane = rem >> 3, j = rem & 7;
    int h = frag >> 1, ks = frag & 1;
    int q4 = lane >> 4, l15 = lane & 15;
    int k = ks * 32 + q4 * 8 + j;
    int n = h * 16 + l15;
    float v;
    if (k < 13) v = W1[k * 128 + n];
    else if (k == 13) v = b1[n];
    else if (k < 16) v = 0.0f;
    else v = W1[(k - 3) * 128 + n];
    wsW[e] = f2bf(v);
  } else {
    int e2 = e - 8192;
    int frag = e2 >> 9, rem = e2 & 511, lane = rem >> 3, j = rem & 7;
    int h2 = frag >> 2, ks = frag & 3;
    int q4 = lane >> 4, l15 = lane & 15;
    int kd = (j < 4) ? (32 * ks + 4 * q4 + j) : (32 * ks + 16 + 4 * q4 + (j - 4));
    int n = h2 * 16 + l15;
    wsW[e] = f2bf(W2[kd * 128 + n]);
  }
}

// ---------------- main fused kernel ----------------
// 256 threads = 4 waves. WG handles 256 rows (=128 queries x 2 passes); each wave owns
// 64 rows as 4 row-tiles (rt): every weight fragment feeds 4 MFMAs. Grid = 2048.
// LDS ~34 KB -> 4 WG/CU (16 waves/CU) with VGPR<=128.
__global__ __launch_bounds__(256, 4) void lisagon_main(
    const float* __restrict__ coord, const float* __restrict__ latent,
    const unsigned short* __restrict__ W1f, const unsigned short* __restrict__ W2f,
    const float* __restrict__ b2, const float* __restrict__ W3,
    const float* __restrict__ b3, float* __restrict__ out) {
  __shared__ __align__(16) unsigned short A1[256 * 64];    // 32 KB input tile
  __shared__ float AREA[256];

  const int t = threadIdx.x;
  const int lane = t & 63, wv = t >> 6;
  const int l15 = lane & 15, q4 = lane >> 4;

  // ---- phase 0: one full input row per thread (no divergence) ----
  {
    const int r = t;                          // local row 0..255
    const int Rg = blockIdx.x * 256 + r;
    const int gq = Rg >> 1, p = Rg & 1;       // p=0 -> vx=-2 pass, p=1 -> vx=0 pass
    const float co = coord[gq];
    float c = (co + (p ? 0.0f : -0.000244140625f)) + 1e-6f;  // vx*rx exact
    c = fminf(fmaxf(c, -1.0f + 1e-6f), 1.0f - 1e-6f);
    double u = ((double)c * 8192.0 + 8191.0) * 0.5;          // exact searchsorted
    int idx = (int)ceil(u);
    idx = min(max(idx, 0), 8191);

    float qc = ((float)(2 * idx + 1) - 8192.0f) * (1.0f / 8192.0f);  // exact grid[idx]
    float rel = (co - qc) * 8192.0f;
    AREA[r] = fabsf(rel) + 1e-9f;

    uint4* A1v = (uint4*)A1;
    // latent chunks 2..7 (prev/self/next rows, 16 floats each) -- issue loads early
    const float4* latv = (const float4*)(latent + (size_t)(gq >> 16) * (8192 * 16));
    int rows3[3];
    rows3[0] = max(idx - 1, 0);
    rows3[1] = idx;
    rows3[2] = min(idx + 1, 8191);
    float4 L[3][4];
#pragma unroll
    for (int s = 0; s < 3; s++)
#pragma unroll
      for (int w = 0; w < 4; w++) L[s][w] = latv[rows3[s] * 4 + w];

    // PE chunks 0..1
    float v[16];
    v[0] = rel;
    float f = rel;
#pragma unroll
    for (int i = 0; i < 6; i++) {
      v[1 + 2 * i] = __sinf(f);
      v[2 + 2 * i] = __cosf(f);
      f = f + f;                 // exact power-of-2 freqs
    }
    v[13] = 1.0f;                // bias-fold slot (W1f row 13 = b1)
    v[14] = 0.0f; v[15] = 0.0f;
#pragma unroll
    for (int ch = 0; ch < 2; ch++) {
      union { uint4 u4; unsigned us[4]; } pkv;
#pragma unroll
      for (int w = 0; w < 4; w++) pkv.us[w] = pk2(v[ch * 8 + 2 * w], v[ch * 8 + 2 * w + 1]);
      A1v[r * 8 + (ch ^ (r & 7))] = pkv.u4;
    }
#pragma unroll
    for (int s = 0; s < 3; s++) {
      union { uint4 u4; unsigned us[4]; } p0, p1;
      p0.us[0] = pk2(L[s][0].x, L[s][0].y); p0.us[1] = pk2(L[s][0].z, L[s][0].w);
      p0.us[2] = pk2(L[s][1].x, L[s][1].y); p0.us[3] = pk2(L[s][1].z, L[s][1].w);
      p1.us[0] = pk2(L[s][2].x, L[s][2].y); p1.us[1] = pk2(L[s][2].z, L[s][2].w);
      p1.us[2] = pk2(L[s][3].x, L[s][3].y); p1.us[3] = pk2(L[s][3].z, L[s][3].w);
      int ch0 = 2 + 2 * s;
      A1v[r * 8 + (ch0 ^ (r & 7))]       = p0.u4;
      A1v[r * 8 + ((ch0 + 1) ^ (r & 7))] = p1.u4;
    }
  }
  __syncthreads();

  const s8v* W1fv = (const s8v*)W1f;
  const s8v* W2fv = (const s8v*)W2f;
  const s8v* A1s  = (const s8v*)A1;
  const int rbase = wv * 64;

  // ---- GEMM1': H1^T[128 x 64] = W1^T @ inp^T (K=64), b1 folded via bias-one ----
  f4v acc1[8][4];
#pragma unroll
  for (int h = 0; h < 8; h++)
#pragma unroll
    for (int rt = 0; rt < 4; rt++) acc1[h][rt] = (f4v){0.f, 0.f, 0.f, 0.f};
#pragma unroll
  for (int ks = 0; ks < 2; ks++) {
    s8v Bf[4];
#pragma unroll
    for (int rt = 0; rt < 4; rt++) {
      int row = rbase + rt * 16 + l15;
      Bf[rt] = A1s[row * 8 + ((ks * 4 + q4) ^ (row & 7))];
    }
#pragma unroll
    for (int h = 0; h < 8; h++) {
      s8v Af = W1fv[(h * 2 + ks) * 64 + lane];
#pragma unroll
      for (int rt = 0; rt < 4; rt++)
        acc1[h][rt] = __builtin_amdgcn_mfma_f32_16x16x32_bf16(Af, Bf[rt], acc1[h][rt], 0, 0, 0);
    }
  }

  // ---- relu + pack; packed regs ARE GEMM2's B-fragments (K-permuted W2f) ----
  unsigned pk[4][8][2];
#pragma unroll
  for (int rt = 0; rt < 4; rt++)
#pragma unroll
    for (int h = 0; h < 8; h++) {
      pk[rt][h][0] = pk2(fmaxf(acc1[h][rt][0], 0.f), fmaxf(acc1[h][rt][1], 0.f));
      pk[rt][h][1] = pk2(fmaxf(acc1[h][rt][2], 0.f), fmaxf(acc1[h][rt][3], 0.f));
    }

  // ---- GEMM2': H2^T[128 x 64] = W2^T @ H1^T (K=128, permuted), b2 as acc-init ----
  f4v acc2[8][4];
#pragma unroll
  for (int h2 = 0; h2 < 8; h2++) {
    f4v b2v = ((const f4v*)b2)[h2 * 4 + q4];   // element i -> hidden2 16h2+4q4+i
#pragma unroll
    for (int rt = 0; rt < 4; rt++) acc2[h2][rt] = b2v;
  }
#pragma unroll
  for (int ks = 0; ks < 4; ks++) {
    union { unsigned u[4]; s8v v; } bb[4];
#pragma unroll
    for (int rt = 0; rt < 4; rt++) {
      bb[rt].u[0] = pk[rt][2 * ks][0];     bb[rt].u[1] = pk[rt][2 * ks][1];
      bb[rt].u[2] = pk[rt][2 * ks + 1][0]; bb[rt].u[3] = pk[rt][2 * ks + 1][1];
    }
#pragma unroll
    for (int h2 = 0; h2 < 8; h2++) {
      s8v Af = W2fv[(h2 * 4 + ks) * 64 + lane];
#pragma unroll
      for (int rt = 0; rt < 4; rt++)
        acc2[h2][rt] = __builtin_amdgcn_mfma_f32_16x16x32_bf16(Af, bb[rt].v, acc2[h2][rt], 0, 0, 0);
    }
  }

  // ---- layer 3: s[rt] = sum_m relu(h2[m]) * W3[m], m = 16h2+4q4+i ----
  float s[4] = {0.f, 0.f, 0.f, 0.f};
#pragma unroll
  for (int h2 = 0; h2 < 8; h2++) {
    float4 w3v = ((const float4*)W3)[h2 * 4 + q4];
#pragma unroll
    for (int rt = 0; rt < 4; rt++) {
      s[rt] += fmaxf(acc2[h2][rt][0], 0.f) * w3v.x;
      s[rt] += fmaxf(acc2[h2][rt][1], 0.f) * w3v.y;
      s[rt] += fmaxf(acc2[h2][rt][2], 0.f) * w3v.z;
      s[rt] += fmaxf(acc2[h2][rt][3], 0.f) * w3v.w;
    }
  }
  const float b3s = b3[0];
#pragma unroll
  for (int rt = 0; rt < 4; rt++) {
    float pred = s[rt];
    pred += __shfl_xor(pred, 16, 64);
    pred += __shfl_xor(pred, 32, 64);
    pred += b3s;
    float other = __shfl_xor(pred, 1, 64);   // (pass0, pass1) at adjacent l15
    if (q4 == 0 && (l15 & 1) == 0) {
      int row0 = rbase + rt * 16 + l15;
      float a0 = AREA[row0], a1 = AREA[row0 + 1];
      float tot = a0 + a1;
      // local_ensemble swap: pred(vx=-2)*a1/tot + pred(vx=0)*a0/tot
      out[(blockIdx.x * 256 + row0) >> 1] = pred * (a1 / tot) + other * (a0 / tot);
    }
  }
}

extern "C" void kernel_launch(void* const* d_in, const int* in_sizes, int n_in,
                              void* d_out, int out_size, void* d_ws, size_t ws_size,
                              hipStream_t stream) {
  const float* coord  = (const float*)d_in[0];
  const float* latent = (const float*)d_in[1];
  const float* W1 = (const float*)d_in[2];
  const float* b1 = (const float*)d_in[3];
  const float* W2 = (const float*)d_in[4];
  const float* b2 = (const float*)d_in[5];
  const float* W3 = (const float*)d_in[6];
  const float* b3 = (const float*)d_in[7];
  float* out = (float*)d_out;
  unsigned short* wsW = (unsigned short*)d_ws;   // [0,8192) W1f, [8192,24576) W2f

  prep_kernel<<<96, 256, 0, stream>>>(W1, b1, W2, wsW);
  lisagon_main<<<2048, 256, 0, stream>>>(coord, latent, wsW, wsW + 8192,
                                         b2, W3, b3, out);
}

// Round 5
// 124.999 us; speedup vs baseline: 2.3125x; 2.3125x over previous
//
#include <hip/hip_runtime.h>
#include <hip/hip_bf16.h>

typedef short s8v __attribute__((ext_vector_type(8)));   // 8 bf16 (4 VGPRs) MFMA A/B frag
typedef float f4v __attribute__((ext_vector_type(4)));   // MFMA C/D frag

__device__ __forceinline__ unsigned short f2bf(float x) {  // RTNE fp32->bf16 (prep only)
  unsigned u = __builtin_bit_cast(unsigned, x);
  u += 0x7fffu + ((u >> 16) & 1u);
  return (unsigned short)(u >> 16);
}
// fast pack: round-to-nearest-away bf16 pair via v_perm (3 VALU ops)
__device__ __forceinline__ unsigned pk2(float a, float b) {
  unsigned ua = __builtin_bit_cast(unsigned, a) + 0x8000u;
  unsigned ub = __builtin_bit_cast(unsigned, b) + 0x8000u;
  return __builtin_amdgcn_perm(ub, ua, 0x07060302u);  // {ub.hi16, ua.hi16}
}

// ---------------- prep: pack W1^T / W2^T as bf16 A-fragments into ws ----------------
// W1f (8192): frag (h,ks): A[m=16h+l15][k=32ks+8q4+j]; k<13 -> W1 row k; k==13 -> b1;
//   14..15 -> 0; k>=16 -> W1 row k-3.
// W2f (16384): frag (h2,ks), K-permuted to match GEMM1-output register order:
//   k-slot 8q4+j (j<4) -> hidden 32ks+4q4+j ; (j>=4) -> hidden 32ks+16+4q4+(j-4).
__global__ void prep_kernel(const float* __restrict__ W1, const float* __restrict__ b1,
                            const float* __restrict__ W2, unsigned short* __restrict__ wsW) {
  int e = blockIdx.x * 256 + threadIdx.x;   // 96*256 = 24576 exactly
  if (e < 8192) {
    int frag = e >> 9, rem = e & 511, lane = rem >> 3, j = rem & 7;
    int h = frag >> 1, ks = frag & 1;
    int q4 = lane >> 4, l15 = lane & 15;
    int k = ks * 32 + q4 * 8 + j;
    int n = h * 16 + l15;
    float v;
    if (k < 13) v = W1[k * 128 + n];
    else if (k == 13) v = b1[n];
    else if (k < 16) v = 0.0f;
    else v = W1[(k - 3) * 128 + n];
    wsW[e] = f2bf(v);
  } else {
    int e2 = e - 8192;
    int frag = e2 >> 9, rem = e2 & 511, lane = rem >> 3, j = rem & 7;
    int h2 = frag >> 2, ks = frag & 3;
    int q4 = lane >> 4, l15 = lane & 15;
    int kd = (j < 4) ? (32 * ks + 4 * q4 + j) : (32 * ks + 16 + 4 * q4 + (j - 4));
    int n = h2 * 16 + l15;
    wsW[e] = f2bf(W2[kd * 128 + n]);
  }
}

// ---------------- main fused kernel ----------------
// 256 threads = 4 waves. WG = 256 rows (128 queries x 2 passes); each wave owns 64 rows
// as 4 row-tiles (rt): every weight fragment feeds 4 MFMAs. Grid = 2048.
// h-outer loop structure keeps ONE output-tile accumulator live at a time:
// peak regs ~= pk(64) + Bf(32) + acc(16) + misc -> fits 3 waves/EU with no spill.
__global__ __launch_bounds__(256, 3) void lisagon_main(
    const float* __restrict__ coord, const float* __restrict__ latent,
    const unsigned short* __restrict__ W1f, const unsigned short* __restrict__ W2f,
    const float* __restrict__ b2, const float* __restrict__ W3,
    const float* __restrict__ b3, float* __restrict__ out) {
  __shared__ __align__(16) unsigned short A1[256 * 64];    // 32 KB input tile
  __shared__ float AREA[256];

  const int t = threadIdx.x;
  const int lane = t & 63, wv = t >> 6;
  const int l15 = lane & 15, q4 = lane >> 4;

  // ---- phase 0: one full input row per thread (no divergence) ----
  {
    const int r = t;                          // local row 0..255
    const int Rg = blockIdx.x * 256 + r;
    const int gq = Rg >> 1, p = Rg & 1;       // p=0 -> vx=-2 pass, p=1 -> vx=0 pass
    const float co = coord[gq];
    float c = (co + (p ? 0.0f : -0.000244140625f)) + 1e-6f;  // vx*rx exact
    c = fminf(fmaxf(c, -1.0f + 1e-6f), 1.0f - 1e-6f);
    double u = ((double)c * 8192.0 + 8191.0) * 0.5;          // exact searchsorted
    int idx = (int)ceil(u);
    idx = min(max(idx, 0), 8191);

    float qc = ((float)(2 * idx + 1) - 8192.0f) * (1.0f / 8192.0f);  // exact grid[idx]
    float rel = (co - qc) * 8192.0f;
    AREA[r] = fabsf(rel) + 1e-9f;

    uint4* A1v = (uint4*)A1;
    // latent chunks 2..7 (prev/self/next rows, 16 floats each) -- issue loads early
    const float4* latv = (const float4*)(latent + (size_t)(gq >> 16) * (8192 * 16));
    int rows3[3];
    rows3[0] = max(idx - 1, 0);
    rows3[1] = idx;
    rows3[2] = min(idx + 1, 8191);
    float4 L[3][4];
#pragma unroll
    for (int s = 0; s < 3; s++)
#pragma unroll
      for (int w = 0; w < 4; w++) L[s][w] = latv[rows3[s] * 4 + w];

    // PE chunks 0..1
    float v[16];
    v[0] = rel;
    float f = rel;
#pragma unroll
    for (int i = 0; i < 6; i++) {
      v[1 + 2 * i] = __sinf(f);
      v[2 + 2 * i] = __cosf(f);
      f = f + f;                 // exact power-of-2 freqs
    }
    v[13] = 1.0f;                // bias-fold slot (W1f row 13 = b1)
    v[14] = 0.0f; v[15] = 0.0f;
#pragma unroll
    for (int ch = 0; ch < 2; ch++) {
      union { uint4 u4; unsigned us[4]; } pkv;
#pragma unroll
      for (int w = 0; w < 4; w++) pkv.us[w] = pk2(v[ch * 8 + 2 * w], v[ch * 8 + 2 * w + 1]);
      A1v[r * 8 + (ch ^ (r & 7))] = pkv.u4;
    }
#pragma unroll
    for (int s = 0; s < 3; s++) {
      union { uint4 u4; unsigned us[4]; } p0, p1;
      p0.us[0] = pk2(L[s][0].x, L[s][0].y); p0.us[1] = pk2(L[s][0].z, L[s][0].w);
      p0.us[2] = pk2(L[s][1].x, L[s][1].y); p0.us[3] = pk2(L[s][1].z, L[s][1].w);
      p1.us[0] = pk2(L[s][2].x, L[s][2].y); p1.us[1] = pk2(L[s][2].z, L[s][2].w);
      p1.us[2] = pk2(L[s][3].x, L[s][3].y); p1.us[3] = pk2(L[s][3].z, L[s][3].w);
      int ch0 = 2 + 2 * s;
      A1v[r * 8 + (ch0 ^ (r & 7))]       = p0.u4;
      A1v[r * 8 + ((ch0 + 1) ^ (r & 7))] = p1.u4;
    }
  }
  __syncthreads();

  const s8v* W1fv = (const s8v*)W1f;
  const s8v* W2fv = (const s8v*)W2f;
  const s8v* A1s  = (const s8v*)A1;
  const int rbase = wv * 64;

  // ---- load all 8 input B-fragments (live across GEMM1) ----
  s8v Bf[2][4];
#pragma unroll
  for (int ks = 0; ks < 2; ks++)
#pragma unroll
    for (int rt = 0; rt < 4; rt++) {
      int row = rbase + rt * 16 + l15;
      Bf[ks][rt] = A1s[row * 8 + ((ks * 4 + q4) ^ (row & 7))];
    }

  // ---- GEMM1' (h-outer): acc for one h live at a time; relu+pack immediately ----
  unsigned pk[4][16];   // [rt][2h+half] -- GEMM2 B-fragments, K-permuted to match W2f
#pragma unroll
  for (int h = 0; h < 8; h++) {
    f4v a[4];
#pragma unroll
    for (int rt = 0; rt < 4; rt++) a[rt] = (f4v){0.f, 0.f, 0.f, 0.f};
#pragma unroll
    for (int ks = 0; ks < 2; ks++) {
      s8v Af = W1fv[(h * 2 + ks) * 64 + lane];
#pragma unroll
      for (int rt = 0; rt < 4; rt++)
        a[rt] = __builtin_amdgcn_mfma_f32_16x16x32_bf16(Af, Bf[ks][rt], a[rt], 0, 0, 0);
    }
#pragma unroll
    for (int rt = 0; rt < 4; rt++) {
      pk[rt][2 * h]     = pk2(fmaxf(a[rt][0], 0.f), fmaxf(a[rt][1], 0.f));
      pk[rt][2 * h + 1] = pk2(fmaxf(a[rt][2], 0.f), fmaxf(a[rt][3], 0.f));
    }
  }

  // ---- GEMM2' (h2-outer): acc2 for one h2 live; consume into layer-3 dot ----
  float s[4] = {0.f, 0.f, 0.f, 0.f};
#pragma unroll
  for (int h2 = 0; h2 < 8; h2++) {
    f4v a2[4];
    f4v b2v = ((const f4v*)b2)[h2 * 4 + q4];   // element i -> hidden2 16h2+4q4+i
#pragma unroll
    for (int rt = 0; rt < 4; rt++) a2[rt] = b2v;
#pragma unroll
    for (int ks = 0; ks < 4; ks++) {
      s8v Af = W2fv[(h2 * 4 + ks) * 64 + lane];
#pragma unroll
      for (int rt = 0; rt < 4; rt++) {
        union { unsigned u[4]; s8v v; } bb;
        bb.u[0] = pk[rt][4 * ks];     bb.u[1] = pk[rt][4 * ks + 1];
        bb.u[2] = pk[rt][4 * ks + 2]; bb.u[3] = pk[rt][4 * ks + 3];
        a2[rt] = __builtin_amdgcn_mfma_f32_16x16x32_bf16(Af, bb.v, a2[rt], 0, 0, 0);
      }
    }
    float4 w3v = ((const float4*)W3)[h2 * 4 + q4];
#pragma unroll
    for (int rt = 0; rt < 4; rt++) {
      s[rt] += fmaxf(a2[rt][0], 0.f) * w3v.x;
      s[rt] += fmaxf(a2[rt][1], 0.f) * w3v.y;
      s[rt] += fmaxf(a2[rt][2], 0.f) * w3v.z;
      s[rt] += fmaxf(a2[rt][3], 0.f) * w3v.w;
    }
  }

  // ---- layer-3 reduce + local-ensemble combine ----
  const float b3s = b3[0];
#pragma unroll
  for (int rt = 0; rt < 4; rt++) {
    float pred = s[rt];
    pred += __shfl_xor(pred, 16, 64);
    pred += __shfl_xor(pred, 32, 64);
    pred += b3s;
    float other = __shfl_xor(pred, 1, 64);   // (pass0, pass1) at adjacent l15
    if (q4 == 0 && (l15 & 1) == 0) {
      int row0 = rbase + rt * 16 + l15;
      float a0 = AREA[row0], a1 = AREA[row0 + 1];
      float tot = a0 + a1;
      // local_ensemble swap: pred(vx=-2)*a1/tot + pred(vx=0)*a0/tot
      out[(blockIdx.x * 256 + row0) >> 1] = pred * (a1 / tot) + other * (a0 / tot);
    }
  }
}

extern "C" void kernel_launch(void* const* d_in, const int* in_sizes, int n_in,
                              void* d_out, int out_size, void* d_ws, size_t ws_size,
                              hipStream_t stream) {
  const float* coord  = (const float*)d_in[0];
  const float* latent = (const float*)d_in[1];
  const float* W1 = (const float*)d_in[2];
  const float* b1 = (const float*)d_in[3];
  const float* W2 = (const float*)d_in[4];
  const float* b2 = (const float*)d_in[5];
  const float* W3 = (const float*)d_in[6];
  const float* b3 = (const float*)d_in[7];
  float* out = (float*)d_out;
  unsigned short* wsW = (unsigned short*)d_ws;   // [0,8192) W1f, [8192,24576) W2f

  prep_kernel<<<96, 256, 0, stream>>>(W1, b1, W2, wsW);
  lisagon_main<<<2048, 256, 0, stream>>>(coord, latent, wsW, wsW + 8192,
                                         b2, W3, b3, out);
}

// Round 6
// 104.908 us; speedup vs baseline: 2.7554x; 1.1915x over previous
//
#include <hip/hip_runtime.h>
#include <hip/hip_bf16.h>

typedef short s8v __attribute__((ext_vector_type(8)));      // 8 bf16 (4 VGPRs) MFMA A/B frag
typedef float f4v __attribute__((ext_vector_type(4)));      // MFMA C/D frag
typedef unsigned u4v __attribute__((ext_vector_type(4)));   // 4 packed bf16-pairs

__device__ __forceinline__ unsigned short f2bf(float x) {  // RTNE fp32->bf16 (prep only)
  unsigned u = __builtin_bit_cast(unsigned, x);
  u += 0x7fffu + ((u >> 16) & 1u);
  return (unsigned short)(u >> 16);
}
// fast pack: round-to-nearest-away bf16 pair via v_perm (3 VALU ops)
__device__ __forceinline__ unsigned pk2(float a, float b) {
  unsigned ua = __builtin_bit_cast(unsigned, a) + 0x8000u;
  unsigned ub = __builtin_bit_cast(unsigned, b) + 0x8000u;
  return __builtin_amdgcn_perm(ub, ua, 0x07060302u);  // {ub.hi16, ua.hi16}
}

// ---------------- prep: pack W1^T / W2^T as bf16 A-fragments into ws ----------------
// W1f (8192): frag (h,ks): A[m=16h+l15][k=32ks+8q4+j]; k<13 -> W1 row k; k==13 -> b1;
//   14..15 -> 0; k>=16 -> W1 row k-3.
// W2f (16384): frag (h2,ks), K-permuted to match GEMM1-output register order:
//   k-slot 8q4+j (j<4) -> hidden 32ks+4q4+j ; (j>=4) -> hidden 32ks+16+4q4+(j-4).
__global__ void prep_kernel(const float* __restrict__ W1, const float* __restrict__ b1,
                            const float* __restrict__ W2, unsigned short* __restrict__ wsW) {
  int e = blockIdx.x * 256 + threadIdx.x;   // 96*256 = 24576 exactly
  if (e < 8192) {
    int frag = e >> 9, rem = e & 511, lane = rem >> 3, j = rem & 7;
    int h = frag >> 1, ks = frag & 1;
    int q4 = lane >> 4, l15 = lane & 15;
    int k = ks * 32 + q4 * 8 + j;
    int n = h * 16 + l15;
    float v;
    if (k < 13) v = W1[k * 128 + n];
    else if (k == 13) v = b1[n];
    else if (k < 16) v = 0.0f;
    else v = W1[(k - 3) * 128 + n];
    wsW[e] = f2bf(v);
  } else {
    int e2 = e - 8192;
    int frag = e2 >> 9, rem = e2 & 511, lane = rem >> 3, j = rem & 7;
    int h2 = frag >> 2, ks = frag & 3;
    int q4 = lane >> 4, l15 = lane & 15;
    int kd = (j < 4) ? (32 * ks + 4 * q4 + j) : (32 * ks + 16 + 4 * q4 + (j - 4));
    int n = h2 * 16 + l15;
    wsW[e] = f2bf(W2[kd * 128 + n]);
  }
}

// ---------------- main fused kernel ----------------
// 256 threads = 4 waves. WG = 256 rows (128 queries x 2 passes); each wave owns 64 rows
// as 4 row-tiles (rt): every weight fragment feeds 4 MFMAs. Grid = 2048.
// (256,2): tighter bounds make the gfx950 backend split the unified file ~50/50
// arch/acc and spill (R4/R5 evidence: reported VGPR == budget/2, WRITE_SIZE 66-700MB).
__global__ __launch_bounds__(256, 2) void lisagon_main(
    const float* __restrict__ coord, const float* __restrict__ latent,
    const unsigned short* __restrict__ W1f, const unsigned short* __restrict__ W2f,
    const float* __restrict__ b2, const float* __restrict__ W3,
    const float* __restrict__ b3, float* __restrict__ out) {
  __shared__ __align__(16) unsigned short A1[256 * 64];    // 32 KB input tile
  __shared__ float AREA[256];

  const int t = threadIdx.x;
  const int lane = t & 63, wv = t >> 6;
  const int l15 = lane & 15, q4 = lane >> 4;

  // ---- phase 0: one full input row per thread (no divergence) ----
  {
    const int r = t;                          // local row 0..255
    const int Rg = blockIdx.x * 256 + r;
    const int gq = Rg >> 1, p = Rg & 1;       // p=0 -> vx=-2 pass, p=1 -> vx=0 pass
    const float co = coord[gq];
    float c = (co + (p ? 0.0f : -0.000244140625f)) + 1e-6f;  // vx*rx exact
    c = fminf(fmaxf(c, -1.0f + 1e-6f), 1.0f - 1e-6f);
    double u = ((double)c * 8192.0 + 8191.0) * 0.5;          // exact searchsorted
    int idx = (int)ceil(u);
    idx = min(max(idx, 0), 8191);

    float qc = ((float)(2 * idx + 1) - 8192.0f) * (1.0f / 8192.0f);  // exact grid[idx]
    float rel = (co - qc) * 8192.0f;
    AREA[r] = fabsf(rel) + 1e-9f;

    uint4* A1v = (uint4*)A1;
    // latent chunks 2..7 (prev/self/next rows, 16 floats each) -- issue loads early
    const float4* latv = (const float4*)(latent + (size_t)(gq >> 16) * (8192 * 16));
    int rows3[3];
    rows3[0] = max(idx - 1, 0);
    rows3[1] = idx;
    rows3[2] = min(idx + 1, 8191);
    float4 L[3][4];
#pragma unroll
    for (int s = 0; s < 3; s++)
#pragma unroll
      for (int w = 0; w < 4; w++) L[s][w] = latv[rows3[s] * 4 + w];

    // PE chunks 0..1
    float v[16];
    v[0] = rel;
    float f = rel;
#pragma unroll
    for (int i = 0; i < 6; i++) {
      v[1 + 2 * i] = __sinf(f);
      v[2 + 2 * i] = __cosf(f);
      f = f + f;                 // exact power-of-2 freqs
    }
    v[13] = 1.0f;                // bias-fold slot (W1f row 13 = b1)
    v[14] = 0.0f; v[15] = 0.0f;
#pragma unroll
    for (int ch = 0; ch < 2; ch++) {
      union { uint4 u4; unsigned us[4]; } pkv;
#pragma unroll
      for (int w = 0; w < 4; w++) pkv.us[w] = pk2(v[ch * 8 + 2 * w], v[ch * 8 + 2 * w + 1]);
      A1v[r * 8 + (ch ^ (r & 7))] = pkv.u4;
    }
#pragma unroll
    for (int s = 0; s < 3; s++) {
      union { uint4 u4; unsigned us[4]; } p0, p1;
      p0.us[0] = pk2(L[s][0].x, L[s][0].y); p0.us[1] = pk2(L[s][0].z, L[s][0].w);
      p0.us[2] = pk2(L[s][1].x, L[s][1].y); p0.us[3] = pk2(L[s][1].z, L[s][1].w);
      p1.us[0] = pk2(L[s][2].x, L[s][2].y); p1.us[1] = pk2(L[s][2].z, L[s][2].w);
      p1.us[2] = pk2(L[s][3].x, L[s][3].y); p1.us[3] = pk2(L[s][3].z, L[s][3].w);
      int ch0 = 2 + 2 * s;
      A1v[r * 8 + (ch0 ^ (r & 7))]       = p0.u4;
      A1v[r * 8 + ((ch0 + 1) ^ (r & 7))] = p1.u4;
    }
  }
  __syncthreads();

  const s8v* W1fv = (const s8v*)W1f;
  const s8v* W2fv = (const s8v*)W2f;
  const s8v* A1s  = (const s8v*)A1;
  const int rbase = wv * 64;

  // ---- load all 8 input B-fragments (live across GEMM1) ----
  s8v Bf[2][4];
#pragma unroll
  for (int ks = 0; ks < 2; ks++)
#pragma unroll
    for (int rt = 0; rt < 4; rt++) {
      int row = rbase + rt * 16 + l15;
      Bf[ks][rt] = A1s[row * 8 + ((ks * 4 + q4) ^ (row & 7))];
    }

  // ---- GEMM1' (h-outer): one h-tile acc live; relu+pack DIRECTLY into bbv lanes ----
  // bbv[rt][ks] is GEMM2's B-fragment for K-chunk ks (K-permuted to match W2f):
  //   lane 2h'+half holds packed pair from GEMM1 output h = 2ks+h', half in {0,1}.
  u4v bbv[4][4];
#pragma unroll
  for (int h = 0; h < 8; h++) {
    f4v a[4];
#pragma unroll
    for (int rt = 0; rt < 4; rt++) a[rt] = (f4v){0.f, 0.f, 0.f, 0.f};
#pragma unroll
    for (int ks = 0; ks < 2; ks++) {
      s8v Af = W1fv[(h * 2 + ks) * 64 + lane];
#pragma unroll
      for (int rt = 0; rt < 4; rt++)
        a[rt] = __builtin_amdgcn_mfma_f32_16x16x32_bf16(Af, Bf[ks][rt], a[rt], 0, 0, 0);
    }
#pragma unroll
    for (int rt = 0; rt < 4; rt++) {
      bbv[rt][h >> 1][2 * (h & 1)]     = pk2(fmaxf(a[rt][0], 0.f), fmaxf(a[rt][1], 0.f));
      bbv[rt][h >> 1][2 * (h & 1) + 1] = pk2(fmaxf(a[rt][2], 0.f), fmaxf(a[rt][3], 0.f));
    }
  }

  // ---- GEMM2' (h2-outer): one h2-tile acc live; b2 as acc-init; consume into dot ----
  float s[4] = {0.f, 0.f, 0.f, 0.f};
#pragma unroll
  for (int h2 = 0; h2 < 8; h2++) {
    f4v a2[4];
    f4v b2v = ((const f4v*)b2)[h2 * 4 + q4];   // element i -> hidden2 16h2+4q4+i
#pragma unroll
    for (int rt = 0; rt < 4; rt++) a2[rt] = b2v;
#pragma unroll
    for (int ks = 0; ks < 4; ks++) {
      s8v Af = W2fv[(h2 * 4 + ks) * 64 + lane];
#pragma unroll
      for (int rt = 0; rt < 4; rt++)
        a2[rt] = __builtin_amdgcn_mfma_f32_16x16x32_bf16(
            Af, __builtin_bit_cast(s8v, bbv[rt][ks]), a2[rt], 0, 0, 0);
    }
    float4 w3v = ((const float4*)W3)[h2 * 4 + q4];
#pragma unroll
    for (int rt = 0; rt < 4; rt++) {
      s[rt] += fmaxf(a2[rt][0], 0.f) * w3v.x;
      s[rt] += fmaxf(a2[rt][1], 0.f) * w3v.y;
      s[rt] += fmaxf(a2[rt][2], 0.f) * w3v.z;
      s[rt] += fmaxf(a2[rt][3], 0.f) * w3v.w;
    }
  }

  // ---- layer-3 reduce + local-ensemble combine ----
  const float b3s = b3[0];
#pragma unroll
  for (int rt = 0; rt < 4; rt++) {
    float pred = s[rt];
    pred += __shfl_xor(pred, 16, 64);
    pred += __shfl_xor(pred, 32, 64);
    pred += b3s;
    float other = __shfl_xor(pred, 1, 64);   // (pass0, pass1) at adjacent l15
    if (q4 == 0 && (l15 & 1) == 0) {
      int row0 = rbase + rt * 16 + l15;
      float a0 = AREA[row0], a1 = AREA[row0 + 1];
      float tot = a0 + a1;
      // local_ensemble swap: pred(vx=-2)*a1/tot + pred(vx=0)*a0/tot
      out[(blockIdx.x * 256 + row0) >> 1] = pred * (a1 / tot) + other * (a0 / tot);
    }
  }
}

extern "C" void kernel_launch(void* const* d_in, const int* in_sizes, int n_in,
                              void* d_out, int out_size, void* d_ws, size_t ws_size,
                              hipStream_t stream) {
  const float* coord  = (const float*)d_in[0];
  const float* latent = (const float*)d_in[1];
  const float* W1 = (const float*)d_in[2];
  const float* b1 = (const float*)d_in[3];
  const float* W2 = (const float*)d_in[4];
  const float* b2 = (const float*)d_in[5];
  const float* W3 = (const float*)d_in[6];
  const float* b3 = (const float*)d_in[7];
  float* out = (float*)d_out;
  unsigned short* wsW = (unsigned short*)d_ws;   // [0,8192) W1f, [8192,24576) W2f

  prep_kernel<<<96, 256, 0, stream>>>(W1, b1, W2, wsW);
  lisagon_main<<<2048, 256, 0, stream>>>(coord, latent, wsW, wsW + 8192,
                                         b2, W3, b3, out);
}